// Round 6
// baseline (335.147 us; speedup 1.0000x reference)
//
#include <hip/hip_runtime.h>

// Problem constants (B=8192, S=32, N=128, K=64, M=3)
#define BATCH 8192
#define NBLK  2048            // 4 batches per block, one per wave
#define EPSF  1e-9f
#define C_LD  36              // |C| LDS tile leading dim (measured 0 conflicts)
#define WLDS  2048            // floats per wave: union{ P dbuf 2x1024, C 32x36=1152 }

typedef float floatx16 __attribute__((ext_vector_type(16)));
typedef short shortx8  __attribute__((ext_vector_type(8)));
typedef __attribute__((address_space(1))) const void g_void;
typedef __attribute__((address_space(3))) void lds_void;

// insert v into descending top-4
__device__ __forceinline__ void ins4(float v, float& t0, float& t1, float& t2, float& t3) {
    float m;
    m = fminf(t0, v); t0 = fmaxf(t0, v); v = m;
    m = fminf(t1, v); t1 = fmaxf(t1, v); v = m;
    m = fminf(t2, v); t2 = fmaxf(t2, v); v = m;
    t3 = fmaxf(t3, v);
}

// merge a second descending top-4 (b0..b3) into t0..t3 (bitonic)
__device__ __forceinline__ void merge4(float& t0, float& t1, float& t2, float& t3,
                                       float b0, float b1, float b2, float b3) {
    float c0 = fmaxf(t0, b3);
    float c1 = fmaxf(t1, b2);
    float c2 = fmaxf(t2, b1);
    float c3 = fmaxf(t3, b0);
    float d0 = fmaxf(c0, c2), d2 = fminf(c0, c2);
    float d1 = fmaxf(c1, c3), d3 = fminf(c1, c3);
    t0 = fmaxf(d0, d1); t1 = fminf(d0, d1);
    t2 = fmaxf(d2, d3); t3 = fminf(d2, d3);
}

// R6 = R5 resubmit with the one new API risk removed: the counter is zeroed
// by a 1-thread kernel (unconditionally graph-capturable) instead of
// hipMemsetAsync inside the captured launch sequence.
//
// FUSED single-kernel version. Body = the verified R2 kernel (81 us,
// passed). Finalization moved in-kernel via last-block-done: each block
// stores its partial, __threadfence (release), atomicAdd a counter (device
// scope); the block observing old==NBLK-1 re-fences (acquire: on gfx950 an
// agent-scope acquire fence invalidates the local L2, so cross-XCD partials
// are fresh) and performs the final reduction in the SAME fixed order as
// the old avl_final -> bitwise-identical output regardless of which block
// is last. No spin-waits anywhere -> no deadlock possible.
__global__ void zero_cnt(unsigned* __restrict__ cnt) { *cnt = 0u; }

__global__ __launch_bounds__(256, 2) void avl_fused(
    const float* __restrict__ y_pred,
    const float* __restrict__ y_true,
    const float* __restrict__ P,   // [B][64][64]
    const float* __restrict__ X,   // [B][32][64]
    float* __restrict__ partial,   // [NBLK][2]: {violation_sum, logmse_sum}
    unsigned* __restrict__ cnt,    // zeroed by zero_cnt each launch
    float* __restrict__ out)       // [3]
{
    __shared__ float lds[4 * WLDS];   // 32768 B
    __shared__ float red[8];
    __shared__ int lastFlag;

    const int tid  = threadIdx.x;
    const int wave = tid >> 6;
    const int lane = tid & 63;
    const int kg   = lane >> 5;   // K-half: this lane covers k = kg*8 + 16*ks + j
    const int m    = lane & 31;   // A row index == B col index == C col index
    const int b    = blockIdx.x * 4 + wave;

    float* ldsw = lds + wave * WLDS;
    const float* Pg = P + (size_t)b * 4096;

    // DMA one 16-row (4KB contiguous) P chunk into buffer `buf`
#define STAGE(buf, kss) do {                                                       \
        const float* _s = Pg + (kss) * 1024 + lane * 4;                            \
        float* _d = ldsw + (buf) * 1024;                                           \
        __builtin_amdgcn_global_load_lds((g_void*)(_s),       (lds_void*)(_d),       16, 0, 0); \
        __builtin_amdgcn_global_load_lds((g_void*)(_s + 256), (lds_void*)(_d + 256), 16, 0, 0); \
        __builtin_amdgcn_global_load_lds((g_void*)(_s + 512), (lds_void*)(_d + 512), 16, 0, 0); \
        __builtin_amdgcn_global_load_lds((g_void*)(_s + 768), (lds_void*)(_d + 768), 16, 0, 0); \
    } while (0)

    // ---- issue x loads (8 dwordx4, A-fragment order) ----
    const float* xg = X + (size_t)b * 2048 + m * 64 + kg * 8;
    float4 xa[4], xb[4];
#pragma unroll
    for (int ks = 0; ks < 4; ++ks) {
        xa[ks] = *(const float4*)(xg + ks * 16);
        xb[ks] = *(const float4*)(xg + ks * 16 + 4);
    }

    // ---- issue first P chunk DMA (overlaps x conversion) ----
    STAGE(0, 0);

    // ---- convert x to hi/lo bf16 A-frags; fold |x| into local top-4 ----
    float t0 = -1.f, t1 = -1.f, t2 = -1.f, t3 = -1.f;
    shortx8 ahi[4], alo[4];
#pragma unroll
    for (int ks = 0; ks < 4; ++ks) {
        const float v[8] = { xa[ks].x, xa[ks].y, xa[ks].z, xa[ks].w,
                             xb[ks].x, xb[ks].y, xb[ks].z, xb[ks].w };
#pragma unroll
        for (int i = 0; i < 8; ++i) {
            const float x = v[i];
            const unsigned bits = __float_as_uint(x);
            ahi[ks][i] = (short)(bits >> 16);
            const float hif = __uint_as_float(bits & 0xFFFF0000u);
            alo[ks][i] = (short)(__float_as_uint(x - hif) >> 16);
            ins4(fabsf(x), t0, t1, t2, t3);
        }
    }

    // ---- K loop: 4 chunks, double-buffered DMA, both 32-col tiles per chunk ----
    floatx16 acc[2];
#pragma unroll
    for (int t = 0; t < 2; ++t)
#pragma unroll
        for (int r = 0; r < 16; ++r) acc[t][r] = 0.f;

#pragma unroll
    for (int ks = 0; ks < 4; ++ks) {
        if (ks < 3) {
            STAGE((ks + 1) & 1, ks + 1);
            asm volatile("s_waitcnt vmcnt(4)" ::: "memory");   // chunk ks landed, ks+1 in flight
        } else {
            asm volatile("s_waitcnt vmcnt(0)" ::: "memory");   // last chunk landed
        }
        __builtin_amdgcn_sched_barrier(0);

        const float* pb = ldsw + (ks & 1) * 1024;
        shortx8 bhi0, blo0, bhi1, blo1;
#pragma unroll
        for (int j = 0; j < 8; ++j) {
            const int row = (kg * 8 + j) * 64 + m;
            const float p0 = pb[row];        // tile 0 (cols 0..31)
            const float p1 = pb[row + 32];   // tile 1 (cols 32..63)
            const unsigned u0 = __float_as_uint(p0);
            bhi0[j] = (short)(u0 >> 16);
            blo0[j] = (short)(__float_as_uint(p0 - __uint_as_float(u0 & 0xFFFF0000u)) >> 16);
            const unsigned u1 = __float_as_uint(p1);
            bhi1[j] = (short)(u1 >> 16);
            blo1[j] = (short)(__float_as_uint(p1 - __uint_as_float(u1 & 0xFFFF0000u)) >> 16);
        }
        acc[0] = __builtin_amdgcn_mfma_f32_32x32x16_bf16(alo[ks], bhi0, acc[0], 0, 0, 0);
        acc[0] = __builtin_amdgcn_mfma_f32_32x32x16_bf16(ahi[ks], blo0, acc[0], 0, 0, 0);
        acc[0] = __builtin_amdgcn_mfma_f32_32x32x16_bf16(ahi[ks], bhi0, acc[0], 0, 0, 0);
        acc[1] = __builtin_amdgcn_mfma_f32_32x32x16_bf16(alo[ks], bhi1, acc[1], 0, 0, 0);
        acc[1] = __builtin_amdgcn_mfma_f32_32x32x16_bf16(ahi[ks], blo1, acc[1], 0, 0, 0);
        acc[1] = __builtin_amdgcn_mfma_f32_32x32x16_bf16(ahi[ks], bhi1, acc[1], 0, 0, 0);
    }

    // all P ds_reads must complete before the union space is overwritten by |C|
    asm volatile("s_waitcnt lgkmcnt(0)" ::: "memory");
    __builtin_amdgcn_sched_barrier(0);

    // ---- per-tile: |C| -> LDS (union with P buffers), row-major top-4 fold ----
    float* Cw = ldsw;
#pragma unroll
    for (int tile = 0; tile < 2; ++tile) {
#pragma unroll
        for (int reg = 0; reg < 16; ++reg) {
            const int row = (reg & 3) + 8 * (reg >> 2) + 4 * kg;
            Cw[row * C_LD + m] = fabsf(acc[tile][reg]);
        }
        const float* cr = Cw + m * C_LD + kg * 16;
#pragma unroll
        for (int t = 0; t < 4; ++t) {
            const float4 c = *(const float4*)(cr + 4 * t);
            ins4(c.x, t0, t1, t2, t3);
            ins4(c.y, t0, t1, t2, t3);
            ins4(c.z, t0, t1, t2, t3);
            ins4(c.w, t0, t1, t2, t3);
        }
    }

    // merge complementary half (lane L and L^32 cover disjoint 64-value sets)
    {
        const float m0 = __shfl_xor(t0, 32, 64);
        const float m1 = __shfl_xor(t1, 32, 64);
        const float m2 = __shfl_xor(t2, 32, 64);
        const float m3 = __shfl_xor(t3, 32, 64);
        merge4(t0, t1, t2, t3, m0, m1, m2, m3);
    }

    float h = t0 / (t3 + EPSF);
#pragma unroll
    for (int msk = 1; msk <= 16; msk <<= 1)
        h = fmaxf(h, __shfl_xor(h, msk, 64));

    if (lane == 0) {
        const float yp = y_pred[b];
        red[wave] = fmaxf(h - yp, 0.f);
        const float lp = log2f(fmaxf(yp, EPSF));
        const float lt = log2f(fmaxf(y_true[b], EPSF));
        const float d = lt - lp;
        red[4 + wave] = d * d;
    }
    __syncthreads();
    if (tid == 0) {
        partial[blockIdx.x * 2 + 0] = red[0] + red[1] + red[2] + red[3];
        partial[blockIdx.x * 2 + 1] = red[4] + red[5] + red[6] + red[7];
        __threadfence();                          // release: partial visible device-wide
        const unsigned old = atomicAdd(cnt, 1u);  // device-scope
        lastFlag = (old == NBLK - 1u) ? 1 : 0;
    }
    __syncthreads();
    if (!lastFlag) return;

    // ---- last block: final reduction, fixed order == old avl_final ----
    __threadfence();   // acquire: agent-scope fence invalidates local L2
    const volatile float* vp = partial;
    float s0 = 0.f, s1 = 0.f;
    for (int i = tid; i < NBLK; i += 256) {
        s0 += vp[2 * i + 0];
        s1 += vp[2 * i + 1];
    }
#pragma unroll
    for (int msk = 1; msk <= 32; msk <<= 1) {
        s0 += __shfl_xor(s0, msk, 64);
        s1 += __shfl_xor(s1, msk, 64);
    }
    __syncthreads();   // red[] reuse
    if (lane == 0) { red[wave] = s0; red[4 + wave] = s1; }
    __syncthreads();
    if (tid == 0) {
        const float vi = (red[0] + red[1] + red[2] + red[3]) * (1.0f / (float)BATCH);
        const float lm = (red[4] + red[5] + red[6] + red[7]) * (1.0f / (float)BATCH);
        out[0] = lm + 0.5f * vi;   // total_loss
        out[1] = lm;               // loss_logmse
        out[2] = vi;               // loss_violation
    }
#undef STAGE
}

extern "C" void kernel_launch(void* const* d_in, const int* in_sizes, int n_in,
                              void* d_out, int out_size, void* d_ws, size_t ws_size,
                              hipStream_t stream)
{
    const float* y_pred = (const float*)d_in[0];
    const float* y_true = (const float*)d_in[1];
    const float* P      = (const float*)d_in[2];
    const float* X      = (const float*)d_in[3];

    float*    partial = (float*)d_ws;                       // NBLK*2 floats = 16 KB
    unsigned* cnt     = (unsigned*)((char*)d_ws + NBLK * 2 * sizeof(float));

    zero_cnt<<<1, 1, 0, stream>>>(cnt);                     // graph-capturable reset
    avl_fused<<<NBLK, 256, 0, stream>>>(y_pred, y_true, P, X, partial, cnt, (float*)d_out);
}

// Round 7
// 244.318 us; speedup vs baseline: 1.3718x; 1.3718x over previous
//
#include <hip/hip_runtime.h>

// Problem constants (B=8192, S=32, N=128, K=64, M=3)
#define BATCH 8192
#define NBLK  2048            // 4 batches per block, one per wave
#define EPSF  1e-9f
#define C_LD  36              // |C| LDS tile leading dim (measured 0 conflicts)
#define WLDS  4096            // floats/wave: 4 P buffers x 1024; C tile unions into buf0-1

typedef float floatx16 __attribute__((ext_vector_type(16)));
typedef short shortx8  __attribute__((ext_vector_type(8)));
typedef __attribute__((address_space(1))) const void g_void;
typedef __attribute__((address_space(3))) void lds_void;

// insert v into descending top-4
__device__ __forceinline__ void ins4(float v, float& t0, float& t1, float& t2, float& t3) {
    float m;
    m = fminf(t0, v); t0 = fmaxf(t0, v); v = m;
    m = fminf(t1, v); t1 = fmaxf(t1, v); v = m;
    m = fminf(t2, v); t2 = fmaxf(t2, v); v = m;
    t3 = fmaxf(t3, v);
}

// merge a second descending top-4 (b0..b3) into t0..t3 (bitonic)
__device__ __forceinline__ void merge4(float& t0, float& t1, float& t2, float& t3,
                                       float b0, float b1, float b2, float b3) {
    float c0 = fmaxf(t0, b3);
    float c1 = fmaxf(t1, b2);
    float c2 = fmaxf(t2, b1);
    float c3 = fmaxf(t3, b0);
    float d0 = fmaxf(c0, c2), d2 = fminf(c0, c2);
    float d1 = fmaxf(c1, c3), d3 = fminf(c1, c3);
    t0 = fmaxf(d0, d1); t1 = fminf(d0, d1);
    t2 = fmaxf(d2, d3); t3 = fminf(d2, d3);
}

// R7: revert the fused structure (per-block device-scope fences cost +89 us;
// the 166 us constant is harness-side and survives fusion). Back to the
// two-kernel layout. New lever on the 81 us body: ALL memory issued up-front
// -- 8 x-loads + 16 P-DMA (4 separate 4KB LDS buffers, no reuse) in one
// burst, then counted vmcnt waits per k-step:
//   after issue: 24 vmem outstanding (x oldest). Compiler waits x at its
//   first use (vmcnt<=16, leaves all chunks in flight). ks0..3 wait
//   vmcnt(12/8/4/0): chunk ks landed, younger chunks still in flight.
// Serial ballooned-latency windows per wave drop ~5 -> ~1-2 (queueing-bound
// regime: thousands of waves oversubscribe L2/HBM queues; per-request
// latency is us-scale, so each *dependent* wait is very expensive).
// C tile unions into P buffers 0-1 after a full lgkmcnt(0) drain.
// LDS 64KB/block -> 2 blocks/CU (8 waves/CU; R4 showed occupancy 8 vs 16
// waves/CU is perf-neutral here). (256,2) avoids R2's spill signature.
__global__ __launch_bounds__(256, 2) void avl_main(
    const float* __restrict__ y_pred,
    const float* __restrict__ y_true,
    const float* __restrict__ P,   // [B][64][64]
    const float* __restrict__ X,   // [B][32][64]
    float* __restrict__ partial)   // [NBLK][2]: {violation_sum, logmse_sum}
{
    __shared__ float lds[4 * WLDS];   // 65536 B
    __shared__ float red[8];

    const int tid  = threadIdx.x;
    const int wave = tid >> 6;
    const int lane = tid & 63;
    const int kg   = lane >> 5;   // K-half: this lane covers k = kg*8 + 16*ks + j
    const int m    = lane & 31;   // A row index == B col index == C col index
    const int b    = blockIdx.x * 4 + wave;

    float* ldsw = lds + wave * WLDS;
    const float* Pg = P + (size_t)b * 4096;

    // DMA one 16-row (4KB contiguous) P chunk into buffer `buf`
#define STAGE(buf, kss) do {                                                       \
        const float* _s = Pg + (kss) * 1024 + lane * 4;                            \
        float* _d = ldsw + (buf) * 1024;                                           \
        __builtin_amdgcn_global_load_lds((g_void*)(_s),       (lds_void*)(_d),       16, 0, 0); \
        __builtin_amdgcn_global_load_lds((g_void*)(_s + 256), (lds_void*)(_d + 256), 16, 0, 0); \
        __builtin_amdgcn_global_load_lds((g_void*)(_s + 512), (lds_void*)(_d + 512), 16, 0, 0); \
        __builtin_amdgcn_global_load_lds((g_void*)(_s + 768), (lds_void*)(_d + 768), 16, 0, 0); \
    } while (0)

    // ---- issue x loads FIRST (oldest in vmem queue -> their wait leaves
    //      the P chunks in flight), then all four P chunk DMAs ----
    const float* xg = X + (size_t)b * 2048 + m * 64 + kg * 8;
    float4 xa[4], xb[4];
#pragma unroll
    for (int ks = 0; ks < 4; ++ks) {
        xa[ks] = *(const float4*)(xg + ks * 16);
        xb[ks] = *(const float4*)(xg + ks * 16 + 4);
    }
    STAGE(0, 0);
    STAGE(1, 1);
    STAGE(2, 2);
    STAGE(3, 3);

    // ---- convert x to hi/lo bf16 A-frags; fold |x| into local top-4
    //      (compiler emits a counted wait for xa/xb here; chunks stay live) ----
    float t0 = -1.f, t1 = -1.f, t2 = -1.f, t3 = -1.f;
    shortx8 ahi[4], alo[4];
#pragma unroll
    for (int ks = 0; ks < 4; ++ks) {
        const float v[8] = { xa[ks].x, xa[ks].y, xa[ks].z, xa[ks].w,
                             xb[ks].x, xb[ks].y, xb[ks].z, xb[ks].w };
#pragma unroll
        for (int i = 0; i < 8; ++i) {
            const float x = v[i];
            const unsigned bits = __float_as_uint(x);
            ahi[ks][i] = (short)(bits >> 16);
            const float hif = __uint_as_float(bits & 0xFFFF0000u);
            alo[ks][i] = (short)(__float_as_uint(x - hif) >> 16);
            ins4(fabsf(x), t0, t1, t2, t3);
        }
    }

    // ---- K loop: chunk ks from its own buffer; counted waits 12/8/4/0 ----
    floatx16 acc[2];
#pragma unroll
    for (int t = 0; t < 2; ++t)
#pragma unroll
        for (int r = 0; r < 16; ++r) acc[t][r] = 0.f;

#pragma unroll
    for (int ks = 0; ks < 4; ++ks) {
        if      (ks == 0) asm volatile("s_waitcnt vmcnt(12)" ::: "memory");
        else if (ks == 1) asm volatile("s_waitcnt vmcnt(8)"  ::: "memory");
        else if (ks == 2) asm volatile("s_waitcnt vmcnt(4)"  ::: "memory");
        else              asm volatile("s_waitcnt vmcnt(0)"  ::: "memory");
        __builtin_amdgcn_sched_barrier(0);

        const float* pb = ldsw + ks * 1024;
        shortx8 bhi0, blo0, bhi1, blo1;
#pragma unroll
        for (int j = 0; j < 8; ++j) {
            const int row = (kg * 8 + j) * 64 + m;
            const float p0 = pb[row];        // tile 0 (cols 0..31)
            const float p1 = pb[row + 32];   // tile 1 (cols 32..63)
            const unsigned u0 = __float_as_uint(p0);
            bhi0[j] = (short)(u0 >> 16);
            blo0[j] = (short)(__float_as_uint(p0 - __uint_as_float(u0 & 0xFFFF0000u)) >> 16);
            const unsigned u1 = __float_as_uint(p1);
            bhi1[j] = (short)(u1 >> 16);
            blo1[j] = (short)(__float_as_uint(p1 - __uint_as_float(u1 & 0xFFFF0000u)) >> 16);
        }
        acc[0] = __builtin_amdgcn_mfma_f32_32x32x16_bf16(alo[ks], bhi0, acc[0], 0, 0, 0);
        acc[0] = __builtin_amdgcn_mfma_f32_32x32x16_bf16(ahi[ks], blo0, acc[0], 0, 0, 0);
        acc[0] = __builtin_amdgcn_mfma_f32_32x32x16_bf16(ahi[ks], bhi0, acc[0], 0, 0, 0);
        acc[1] = __builtin_amdgcn_mfma_f32_32x32x16_bf16(alo[ks], bhi1, acc[1], 0, 0, 0);
        acc[1] = __builtin_amdgcn_mfma_f32_32x32x16_bf16(ahi[ks], blo1, acc[1], 0, 0, 0);
        acc[1] = __builtin_amdgcn_mfma_f32_32x32x16_bf16(ahi[ks], bhi1, acc[1], 0, 0, 0);
    }

    // all P ds_reads must complete before buffers 0-1 are overwritten by |C|
    asm volatile("s_waitcnt lgkmcnt(0)" ::: "memory");
    __builtin_amdgcn_sched_barrier(0);

    // ---- per-tile: |C| -> LDS (union with P buf0-1), row-major top-4 fold ----
    float* Cw = ldsw;
#pragma unroll
    for (int tile = 0; tile < 2; ++tile) {
#pragma unroll
        for (int reg = 0; reg < 16; ++reg) {
            const int row = (reg & 3) + 8 * (reg >> 2) + 4 * kg;
            Cw[row * C_LD + m] = fabsf(acc[tile][reg]);
        }
        const float* cr = Cw + m * C_LD + kg * 16;
#pragma unroll
        for (int t = 0; t < 4; ++t) {
            const float4 c = *(const float4*)(cr + 4 * t);
            ins4(c.x, t0, t1, t2, t3);
            ins4(c.y, t0, t1, t2, t3);
            ins4(c.z, t0, t1, t2, t3);
            ins4(c.w, t0, t1, t2, t3);
        }
    }

    // merge complementary half (lane L and L^32 cover disjoint 64-value sets)
    {
        const float m0 = __shfl_xor(t0, 32, 64);
        const float m1 = __shfl_xor(t1, 32, 64);
        const float m2 = __shfl_xor(t2, 32, 64);
        const float m3 = __shfl_xor(t3, 32, 64);
        merge4(t0, t1, t2, t3, m0, m1, m2, m3);
    }

    float h = t0 / (t3 + EPSF);
#pragma unroll
    for (int msk = 1; msk <= 16; msk <<= 1)
        h = fmaxf(h, __shfl_xor(h, msk, 64));

    if (lane == 0) {
        const float yp = y_pred[b];
        red[wave] = fmaxf(h - yp, 0.f);
        const float lp = log2f(fmaxf(yp, EPSF));
        const float lt = log2f(fmaxf(y_true[b], EPSF));
        const float d = lt - lp;
        red[4 + wave] = d * d;
    }
    __syncthreads();
    if (tid == 0) {
        partial[blockIdx.x * 2 + 0] = red[0] + red[1] + red[2] + red[3];
        partial[blockIdx.x * 2 + 1] = red[4] + red[5] + red[6] + red[7];
    }
#undef STAGE
}

__global__ __launch_bounds__(256) void avl_final(
    const float* __restrict__ partial, float* __restrict__ out)
{
    const int tid  = threadIdx.x;
    const int wave = tid >> 6;
    const int lane = tid & 63;
    float s0 = 0.f, s1 = 0.f;
    for (int i = tid; i < NBLK; i += 256) {
        s0 += partial[2 * i + 0];
        s1 += partial[2 * i + 1];
    }
#pragma unroll
    for (int msk = 1; msk <= 32; msk <<= 1) {
        s0 += __shfl_xor(s0, msk, 64);
        s1 += __shfl_xor(s1, msk, 64);
    }
    __shared__ float r0[4], r1[4];
    if (lane == 0) { r0[wave] = s0; r1[wave] = s1; }
    __syncthreads();
    if (tid == 0) {
        const float vi = (r0[0] + r0[1] + r0[2] + r0[3]) * (1.0f / (float)BATCH);
        const float lm = (r1[0] + r1[1] + r1[2] + r1[3]) * (1.0f / (float)BATCH);
        out[0] = lm + 0.5f * vi;   // total_loss
        out[1] = lm;               // loss_logmse
        out[2] = vi;               // loss_violation
    }
}

extern "C" void kernel_launch(void* const* d_in, const int* in_sizes, int n_in,
                              void* d_out, int out_size, void* d_ws, size_t ws_size,
                              hipStream_t stream)
{
    const float* y_pred = (const float*)d_in[0];
    const float* y_true = (const float*)d_in[1];
    const float* P      = (const float*)d_in[2];
    const float* X      = (const float*)d_in[3];

    float* partial = (float*)d_ws;   // NBLK*2 floats = 16 KB
    avl_main<<<NBLK, 256, 0, stream>>>(y_pred, y_true, P, X, partial);
    avl_final<<<1, 256, 0, stream>>>(partial, (float*)d_out);
}